// Round 1
// baseline (2501.236 us; speedup 1.0000x reference)
//
#include <hip/hip_runtime.h>
#include <math.h>

// BiDAF attention, fp32 correctness-first baseline.
// B=64, T=2048, J=256, D=200. Output g: (B,T,4D).
//
// Kernel plan:
//  k_cterm : cterm[b][j] = dot(u[b,j], w_u) + (b_h+b_u+b_hu)
//  k_main  : per (b, 16-row t-tile): s = hw @ u^T + rt + ct (flash online softmax
//            over j-chunks of 32), c2q accumulated in registers, writes
//            g[:, 0:D]=h, g[:, D:2D]=c2q, g[:, 2D:3D]=h*c2q, m[b][t]=max_j s
//  k_stats : per b: M=max_t m, iZ=1/sum exp(m-M)
//  k_q2c   : q2c[b][d] = sum_t exp(m-M)*iZ * h[b,t,d]   (atomic partials)
//  k_g3    : g[:, 3D:4D] = h * q2c[b]

#define B_ 64
#define T_ 2048
#define J_ 256
#define D_ 200
#define TT 16       // t-rows per k_main block
#define JCH 32      // j-chunk staged in LDS
#define NCH (J_ / JCH)
#define ULD 204     // padded LDS row stride (floats), mult of 4; 204%32=12 -> <=2-way conflicts
#define SLD 33

__global__ __launch_bounds__(256) void k_cterm(
    const float* __restrict__ u, const float* __restrict__ w_u,
    const float* __restrict__ b_h, const float* __restrict__ b_u,
    const float* __restrict__ b_hu, float* __restrict__ cterm) {
  const int wave = (blockIdx.x * 256 + threadIdx.x) >> 6;  // one wave per (b,j) row
  const int lane = threadIdx.x & 63;
  if (wave >= B_ * J_) return;
  const float* row = u + (size_t)wave * D_;
  float p = 0.f;
  for (int d = lane; d < D_; d += 64) p += row[d] * w_u[d];
  for (int off = 32; off > 0; off >>= 1) p += __shfl_xor(p, off, 64);
  if (lane == 0) cterm[wave] = p + b_h[0] + b_u[0] + b_hu[0];
}

__global__ __launch_bounds__(256) void k_main(
    const float* __restrict__ h, const float* __restrict__ u,
    const float* __restrict__ w_h, const float* __restrict__ w_hu,
    const float* __restrict__ cterm, float* __restrict__ g,
    float* __restrict__ m_out) {
  __shared__ __align__(16) float hl[TT][ULD];   // raw h tile
  __shared__ __align__(16) float hw[TT][ULD];   // h * w_hu
  __shared__ __align__(16) float ul[JCH][ULD];  // u chunk
  __shared__ float sl[TT][SLD];                 // p (exp) values for chunk
  __shared__ float al[TT], ll[TT], rt[TT];
  __shared__ float ctl[J_];

  const int tid = threadIdx.x;
  const int b = blockIdx.y;
  const int t0 = blockIdx.x * TT;
  const int t = tid >> 4;   // 0..15 : row (same in both layouts)
  const int jg = tid & 15;  // layout A: j-group ; layout B: d16 group

  // ---- stage h tile (coalesced float4), build hw = h*w_hu ----
  for (int idx = tid; idx < TT * (D_ / 4); idx += 256) {
    const int r = idx / (D_ / 4), c = (idx % (D_ / 4)) * 4;
    const float4 hv = *(const float4*)(h + ((size_t)(b * T_ + t0 + r)) * D_ + c);
    const float4 wv = *(const float4*)(w_hu + c);
    *(float4*)&hl[r][c] = hv;
    const float4 hwv = make_float4(hv.x * wv.x, hv.y * wv.y, hv.z * wv.z, hv.w * wv.w);
    *(float4*)&hw[r][c] = hwv;
  }
  if (tid < J_) ctl[tid] = cterm[b * J_ + tid];
  __syncthreads();

  // ---- rterm[t] = dot(h[t], w_h), 16 lanes per row ----
  {
    float p = 0.f;
    for (int d = jg; d < D_; d += 16) p += hl[t][d] * w_h[d];
    p += __shfl_xor(p, 8, 16); p += __shfl_xor(p, 4, 16);
    p += __shfl_xor(p, 2, 16); p += __shfl_xor(p, 1, 16);
    if (jg == 0) rt[t] = p;
  }
  __syncthreads();
  const float rt_t = rt[t];

  float m_run = -INFINITY, l_run = 0.f;
  float4 c0 = make_float4(0.f, 0.f, 0.f, 0.f), c1 = c0, c2 = c0, c3 = c0;
  const int d0 = jg * 4;  // layout B: this thread owns d = d0 + {0..3} + 64*kk

  for (int ch = 0; ch < NCH; ++ch) {
    __syncthreads();  // previous chunk's ul/sl consumers done
    // ---- stage u chunk ----
    const float* ub = u + ((size_t)(b * J_ + ch * JCH)) * D_;
    for (int idx = tid; idx < JCH * (D_ / 4); idx += 256) {
      const int r = idx / (D_ / 4), c = (idx % (D_ / 4)) * 4;
      *(float4*)&ul[r][c] = *(const float4*)(ub + r * D_ + c);
    }
    __syncthreads();

    // ---- s chunk: thread computes s for (t, jg) and (t, jg+16) ----
    float4 a0 = make_float4(0.f, 0.f, 0.f, 0.f), a1 = a0;
    for (int dd = 0; dd < D_; dd += 4) {
      const float4 hv = *(const float4*)&hw[t][dd];
      const float4 u0 = *(const float4*)&ul[jg][dd];
      const float4 u1 = *(const float4*)&ul[jg + 16][dd];
      a0.x = fmaf(hv.x, u0.x, a0.x); a0.y = fmaf(hv.y, u0.y, a0.y);
      a0.z = fmaf(hv.z, u0.z, a0.z); a0.w = fmaf(hv.w, u0.w, a0.w);
      a1.x = fmaf(hv.x, u1.x, a1.x); a1.y = fmaf(hv.y, u1.y, a1.y);
      a1.z = fmaf(hv.z, u1.z, a1.z); a1.w = fmaf(hv.w, u1.w, a1.w);
    }
    const float s0 = (a0.x + a0.y) + (a0.z + a0.w) + rt_t + ctl[ch * JCH + jg];
    const float s1 = (a1.x + a1.y) + (a1.z + a1.w) + rt_t + ctl[ch * JCH + jg + 16];

    // ---- online softmax update over this chunk (16 lanes per row) ----
    float mx = fmaxf(s0, s1);
    mx = fmaxf(mx, __shfl_xor(mx, 8, 16)); mx = fmaxf(mx, __shfl_xor(mx, 4, 16));
    mx = fmaxf(mx, __shfl_xor(mx, 2, 16)); mx = fmaxf(mx, __shfl_xor(mx, 1, 16));
    const float m_new = fmaxf(m_run, mx);
    const float alpha = __expf(m_run - m_new);  // first chunk: exp(-inf)=0
    const float p0 = __expf(s0 - m_new);
    const float p1 = __expf(s1 - m_new);
    float ps = p0 + p1;
    ps += __shfl_xor(ps, 8, 16); ps += __shfl_xor(ps, 4, 16);
    ps += __shfl_xor(ps, 2, 16); ps += __shfl_xor(ps, 1, 16);
    l_run = l_run * alpha + ps;
    m_run = m_new;
    sl[t][jg] = p0;
    sl[t][jg + 16] = p1;
    if (jg == 0) al[t] = alpha;
    __syncthreads();

    // ---- c2q accumulate (layout B: thread owns d = d0+{0..3}+64*kk) ----
    const float av = al[t];
    c0.x *= av; c0.y *= av; c0.z *= av; c0.w *= av;
    c1.x *= av; c1.y *= av; c1.z *= av; c1.w *= av;
    c2.x *= av; c2.y *= av; c2.z *= av; c2.w *= av;
    c3.x *= av; c3.y *= av; c3.z *= av; c3.w *= av;
    for (int j = 0; j < JCH; ++j) {
      const float p = sl[t][j];
      const float4 u0 = *(const float4*)&ul[j][d0];
      const float4 u1 = *(const float4*)&ul[j][d0 + 64];
      const float4 u2 = *(const float4*)&ul[j][d0 + 128];
      c0.x = fmaf(p, u0.x, c0.x); c0.y = fmaf(p, u0.y, c0.y);
      c0.z = fmaf(p, u0.z, c0.z); c0.w = fmaf(p, u0.w, c0.w);
      c1.x = fmaf(p, u1.x, c1.x); c1.y = fmaf(p, u1.y, c1.y);
      c1.z = fmaf(p, u1.z, c1.z); c1.w = fmaf(p, u1.w, c1.w);
      c2.x = fmaf(p, u2.x, c2.x); c2.y = fmaf(p, u2.y, c2.y);
      c2.z = fmaf(p, u2.z, c2.z); c2.w = fmaf(p, u2.w, c2.w);
      if (d0 < 8) {  // d0+192 < 200 only for jg<2
        const float4 u3 = *(const float4*)&ul[j][d0 + 192];
        c3.x = fmaf(p, u3.x, c3.x); c3.y = fmaf(p, u3.y, c3.y);
        c3.z = fmaf(p, u3.z, c3.z); c3.w = fmaf(p, u3.w, c3.w);
      }
    }
  }

  if (jg == 0) {
    ll[t] = l_run;
    m_out[b * T_ + t0 + t] = m_run;
  }
  __syncthreads();

  // ---- epilogue: g[:,0:D]=h, g[:,D:2D]=c2q, g[:,2D:3D]=h*c2q ----
  const float inv = 1.f / ll[t];
  const size_t base = ((size_t)(b * T_ + t0 + t)) * (4 * D_);
  {
    const float4 hv = *(const float4*)&hl[t][d0];
    const float4 cc = make_float4(c0.x * inv, c0.y * inv, c0.z * inv, c0.w * inv);
    *(float4*)(g + base + d0) = hv;
    *(float4*)(g + base + D_ + d0) = cc;
    *(float4*)(g + base + 2 * D_ + d0) = make_float4(hv.x * cc.x, hv.y * cc.y, hv.z * cc.z, hv.w * cc.w);
  }
  {
    const float4 hv = *(const float4*)&hl[t][d0 + 64];
    const float4 cc = make_float4(c1.x * inv, c1.y * inv, c1.z * inv, c1.w * inv);
    *(float4*)(g + base + d0 + 64) = hv;
    *(float4*)(g + base + D_ + d0 + 64) = cc;
    *(float4*)(g + base + 2 * D_ + d0 + 64) = make_float4(hv.x * cc.x, hv.y * cc.y, hv.z * cc.z, hv.w * cc.w);
  }
  {
    const float4 hv = *(const float4*)&hl[t][d0 + 128];
    const float4 cc = make_float4(c2.x * inv, c2.y * inv, c2.z * inv, c2.w * inv);
    *(float4*)(g + base + d0 + 128) = hv;
    *(float4*)(g + base + D_ + d0 + 128) = cc;
    *(float4*)(g + base + 2 * D_ + d0 + 128) = make_float4(hv.x * cc.x, hv.y * cc.y, hv.z * cc.z, hv.w * cc.w);
  }
  if (d0 < 8) {
    const float4 hv = *(const float4*)&hl[t][d0 + 192];
    const float4 cc = make_float4(c3.x * inv, c3.y * inv, c3.z * inv, c3.w * inv);
    *(float4*)(g + base + d0 + 192) = hv;
    *(float4*)(g + base + D_ + d0 + 192) = cc;
    *(float4*)(g + base + 2 * D_ + d0 + 192) = make_float4(hv.x * cc.x, hv.y * cc.y, hv.z * cc.z, hv.w * cc.w);
  }
}

__global__ __launch_bounds__(256) void k_stats(
    const float* __restrict__ m, float* __restrict__ Mb, float* __restrict__ iZb) {
  const int b = blockIdx.x, tid = threadIdx.x;
  __shared__ float redm[4], reds[4];
  const float* mb = m + b * T_;
  float mx = -INFINITY;
  for (int tt = tid; tt < T_; tt += 256) mx = fmaxf(mx, mb[tt]);
  for (int off = 32; off > 0; off >>= 1) mx = fmaxf(mx, __shfl_xor(mx, off, 64));
  if ((tid & 63) == 0) redm[tid >> 6] = mx;
  __syncthreads();
  const float M = fmaxf(fmaxf(redm[0], redm[1]), fmaxf(redm[2], redm[3]));
  float se = 0.f;
  for (int tt = tid; tt < T_; tt += 256) se += __expf(mb[tt] - M);
  for (int off = 32; off > 0; off >>= 1) se += __shfl_xor(se, off, 64);
  if ((tid & 63) == 0) reds[tid >> 6] = se;
  __syncthreads();
  if (tid == 0) {
    Mb[b] = M;
    iZb[b] = 1.f / (reds[0] + reds[1] + reds[2] + reds[3]);
  }
}

__global__ __launch_bounds__(256) void k_q2c(
    const float* __restrict__ h, const float* __restrict__ m,
    const float* __restrict__ Mb, const float* __restrict__ iZb,
    float* __restrict__ q2c) {
  const int b = blockIdx.y;
  const int t0 = blockIdx.x * 32;
  const int tid = threadIdx.x;
  __shared__ float wl[32];
  if (tid < 32) wl[tid] = __expf(m[b * T_ + t0 + tid] - Mb[b]) * iZb[b];
  __syncthreads();
  if (tid < D_) {
    float acc = 0.f;
    const float* hb = h + ((size_t)(b * T_ + t0)) * D_ + tid;
    for (int tt = 0; tt < 32; ++tt) acc = fmaf(wl[tt], hb[(size_t)tt * D_], acc);
    atomicAdd(&q2c[b * D_ + tid], acc);
  }
}

__global__ __launch_bounds__(256) void k_g3(
    const float* __restrict__ h, const float* __restrict__ q2c,
    float* __restrict__ g) {
  const unsigned i = blockIdx.x * 256u + threadIdx.x;
  if (i >= (unsigned)(B_ * T_ * D_)) return;
  const unsigned row = i / D_;       // b*T + t
  const unsigned d = i - row * D_;
  const unsigned b = row >> 11;      // T_ = 2048
  g[(size_t)row * (4 * D_) + 3 * D_ + d] = h[i] * q2c[b * D_ + d];
}

extern "C" void kernel_launch(void* const* d_in, const int* in_sizes, int n_in,
                              void* d_out, int out_size, void* d_ws, size_t ws_size,
                              hipStream_t stream) {
  const float* h    = (const float*)d_in[0];
  const float* u    = (const float*)d_in[1];
  const float* w_h  = (const float*)d_in[2];
  const float* b_h  = (const float*)d_in[3];
  const float* w_u  = (const float*)d_in[4];
  const float* b_u  = (const float*)d_in[5];
  const float* w_hu = (const float*)d_in[6];
  const float* b_hu = (const float*)d_in[7];
  float* g = (float*)d_out;

  float* ws    = (float*)d_ws;
  float* cterm = ws;                       // B*J      = 16384
  float* m     = ws + 16384;               // B*T      = 131072
  float* Mb    = ws + 16384 + 131072;      // B        = 64
  float* iZb   = Mb + 64;                  // B        = 64
  float* q2c   = iZb + 64;                 // B*D      = 12800

  hipMemsetAsync(q2c, 0, (size_t)B_ * D_ * sizeof(float), stream);

  k_cterm<<<(B_ * J_) / 4, 256, 0, stream>>>(u, w_u, b_h, b_u, b_hu, cterm);
  k_main<<<dim3(T_ / TT, B_), 256, 0, stream>>>(h, u, w_h, w_hu, cterm, g, m);
  k_stats<<<B_, 256, 0, stream>>>(m, Mb, iZb);
  k_q2c<<<dim3(T_ / 32, B_), 256, 0, stream>>>(h, m, Mb, iZb, q2c);
  k_g3<<<(B_ * T_ * D_ + 255) / 256, 256, 0, stream>>>(h, q2c, g);
}